// Round 1
// baseline (91.541 us; speedup 1.0000x reference)
//
#include <hip/hip_runtime.h>
#include <stdint.h>

#define IN_C 64
#define HH 256
#define WW 256
#define HW (HH * WW)
#define OUT_C 128
#define OH 254
#define OW 254
#define OHW (OH * OW)

#define XR 4     // staged input rows (2 out rows + 2 halo)
#define XW 66    // staged input width (64 + 2 halo)
#define CPAD 72  // channel stride in shorts: 144 B -> b128 B-frag reads bank-balanced

typedef __attribute__((ext_vector_type(4))) float f32x4;
typedef __attribute__((ext_vector_type(8))) __bf16 bf16x8;

__device__ __forceinline__ unsigned short f2bf(float f) {
  union { float f; unsigned u; } v; v.f = f;
  unsigned r = v.u + 0x7FFFu + ((v.u >> 16) & 1u);  // RNE (inputs finite/normal)
  return (unsigned short)(r >> 16);
}

// Weights -> A-fragment order bf16:
// wt[tap][ch][mt][lane][j] = bf16( W[o=mt*16+(lane&15)][c=ch*32+(lane>>4)*8+j][tap] )
// A-frag load is a verbatim per-lane global_load_dwordx4 (L1/L2-resident, no LDS).
__global__ void prep_w(const float* __restrict__ w, unsigned short* __restrict__ wt) {
  const int idx = blockIdx.x * 256 + threadIdx.x;
  if (idx >= 9 * 8192) return;
  const int j    = idx & 7;
  const int lane = (idx >> 3) & 63;
  const int mt   = (idx >> 9) & 7;
  const int ch   = (idx >> 12) & 1;
  const int tap  = idx >> 13;
  const int o = mt * 16 + (lane & 15);
  const int c = ch * 32 + (lane >> 4) * 8 + j;
  wt[idx] = f2bf(w[(o * IN_C + c) * 9 + tap]);
}

// 256-thread block: 2 output rows x 64 px x 128 ch. 4 waves = (row 0..1, mhalf 0..1).
// Grid (4,127) = 508 blocks -> 3 resident blocks/CU: one block's HBM staging overlaps
// another's MFMA compute (the old 256-block / 1-per-CU layout serialized the phases).
__global__ __launch_bounds__(256, 3) void conv_mfma(
    const float* __restrict__ x, const unsigned short* __restrict__ wt,
    const float* __restrict__ bias, float* __restrict__ out) {
  __shared__ __align__(16) unsigned short Xs[XR * XW * CPAD];  // 38016 B

  const int tid  = threadIdx.x;
  const int wave = tid >> 6;
  const int lane = tid & 63;
  const int x0 = blockIdx.x * 64;   // 0,64,128,192 (mask stores at xc >= 254)
  const int y0 = blockIdx.y * 2;    // 0..252; rows y0..y0+3 staged, all <= 255: no clamp

  const int mhalf = wave & 1;   // half of the 128 out-channels
  const int row   = wave >> 1;  // which of the 2 output rows
  const int nlane = lane & 15;
  const int quad  = lane >> 4;

  // A-frag base; chunk-0 prefetch first — in flight across the staging phase
  const bf16x8* __restrict__ Wp = ((const bf16x8*)wt) + lane + (mhalf * 4) * 64;
  bf16x8 afA[4], afB[4];
#pragma unroll
  for (int mt = 0; mt < 4; ++mt) afA[mt] = Wp[mt * 64];

  // ---- stage Xs: Xs[r][xx][c] = bf16(x[c][y0+r][x0+xx])
  // thread = (cq 0..15, xh 0..15); ALL 18 loads (2 halo + 16 vector) issued before
  // any convert -> ~64 KB in flight per block for HBM latency hiding.
  {
    const int cq = tid & 15;          // channels cq*4 .. cq*4+3
    const int xh = tid >> 4;          // xx = xh*4 .. xh*4+3

    // tail halo xx = 64,65 : 4 rows x 2 px x 64 ch (x-clamped; feeds masked cols only)
    int hc[2], hr[2], hx[2];
    float hv[2];
#pragma unroll
    for (int h = 0; h < 2; ++h) {
      const int k = tid + h * 256;
      hc[h] = k & 63;
      const int q = k >> 6;           // 0..7
      hx[h] = 64 + (q & 1);
      hr[h] = q >> 1;                 // 0..3
      int xg = x0 + hx[h];
      if (xg > WW - 1) xg = WW - 1;
      hv[h] = x[hc[h] * HW + (y0 + hr[h]) * WW + xg];
    }

    f32x4 vv[4][4];
#pragma unroll
    for (int r = 0; r < 4; ++r) {
      const float* bx = x + (y0 + r) * WW + x0 + xh * 4;
#pragma unroll
      for (int cc = 0; cc < 4; ++cc)
        vv[r][cc] = *(const f32x4*)(bx + (cq * 4 + cc) * HW);
    }

    // packed ds_write_b64 (4 ch per write): 16 lanes of one xh-group cover all 32
    // banks; xh-groups alias 2-way = free.
#pragma unroll
    for (int r = 0; r < 4; ++r) {
#pragma unroll
      for (int xxi = 0; xxi < 4; ++xxi) {
        unsigned u0 = (unsigned)f2bf(vv[r][0][xxi]) | ((unsigned)f2bf(vv[r][1][xxi]) << 16);
        unsigned u1 = (unsigned)f2bf(vv[r][2][xxi]) | ((unsigned)f2bf(vv[r][3][xxi]) << 16);
        *(uint2*)&Xs[(r * XW + xh * 4 + xxi) * CPAD + cq * 4] = make_uint2(u0, u1);
      }
    }
#pragma unroll
    for (int h = 0; h < 2; ++h)
      Xs[(hr[h] * XW + hx[h]) * CPAD + hc[h]] = f2bf(hv[h]);
  }

  // accumulators init with bias (C/D row = quad*4+reg = out-ch)
  f32x4 acc[4][4];
#pragma unroll
  for (int mt = 0; mt < 4; ++mt) {
    const f32x4 bv = *(const f32x4*)(bias + (mhalf * 4 + mt) * 16 + quad * 4);
#pragma unroll
    for (int nt = 0; nt < 4; ++nt) acc[mt][nt] = bv;
  }

  __syncthreads();  // Xs ready — the only barrier in the kernel

  // ---- 9 taps x 2 ch-chunks; A double-buffered one chunk ahead, all indices static
#pragma unroll 1
  for (int pair = 0; pair < 9; ++pair) {
    const int ky = pair / 3;
    const int kx = pair - ky * 3;
    const int r = row + ky;           // 0..3
    const unsigned short* xrow = &Xs[(r * XW + kx) * CPAD + quad * 8];

    // prefetch odd chunk (tap=pair, ch=1)
#pragma unroll
    for (int mt = 0; mt < 4; ++mt) afB[mt] = Wp[((2 * pair + 1) * 8 + mt) * 64];

    {  // compute even chunk (ch = 0) with afA
      bf16x8 bfr[4];
#pragma unroll
      for (int nt = 0; nt < 4; ++nt)
        bfr[nt] = *(const bf16x8*)&xrow[(nt * 16 + nlane) * CPAD];
#pragma unroll
      for (int mt = 0; mt < 4; ++mt)
#pragma unroll
        for (int nt = 0; nt < 4; ++nt)
          acc[mt][nt] = __builtin_amdgcn_mfma_f32_16x16x32_bf16(afA[mt], bfr[nt], acc[mt][nt], 0, 0, 0);
    }

    if (pair < 8) {  // prefetch next pair's even chunk
#pragma unroll
      for (int mt = 0; mt < 4; ++mt) afA[mt] = Wp[((2 * pair + 2) * 8 + mt) * 64];
    }

    {  // compute odd chunk (ch = 1) with afB
      bf16x8 bfr[4];
#pragma unroll
      for (int nt = 0; nt < 4; ++nt)
        bfr[nt] = *(const bf16x8*)&xrow[(nt * 16 + nlane) * CPAD + 32];
#pragma unroll
      for (int mt = 0; mt < 4; ++mt)
#pragma unroll
        for (int nt = 0; nt < 4; ++nt)
          acc[mt][nt] = __builtin_amdgcn_mfma_f32_16x16x32_bf16(afB[mt], bfr[nt], acc[mt][nt], 0, 0, 0);
    }
  }

  // ---- epilogue: C/D col = lane&15 (pixel), row = quad*4+reg (out-ch); plain stores
  const int y = y0 + row;  // always < 254: no y mask needed
#pragma unroll
  for (int mt = 0; mt < 4; ++mt) {
    const int obase = (mhalf * 4 + mt) * 16 + quad * 4;
#pragma unroll
    for (int nt = 0; nt < 4; ++nt) {
      const int xc = x0 + nt * 16 + nlane;
      if (xc < OW) {
        float* dst = out + obase * OHW + y * OW + xc;
#pragma unroll
        for (int reg = 0; reg < 4; ++reg)
          dst[reg * OHW] = acc[mt][nt][reg];
      }
    }
  }
}

extern "C" void kernel_launch(void* const* d_in, const int* in_sizes, int n_in,
                              void* d_out, int out_size, void* d_ws, size_t ws_size,
                              hipStream_t stream) {
  const float* x = (const float*)d_in[0];
  const float* w = (const float*)d_in[1];
  const float* b = (const float*)d_in[2];
  float* out = (float*)d_out;
  unsigned short* wt = (unsigned short*)d_ws;  // 147456 B fragment-ordered bf16 weights

  prep_w<<<dim3(288), dim3(256), 0, stream>>>(w, wt);
  conv_mfma<<<dim3(4, 127), dim3(256), 0, stream>>>(x, wt, b, out);
}